// Round 1
// baseline (500.290 us; speedup 1.0000x reference)
//
#include <hip/hip_runtime.h>
#include <hip/hip_bf16.h>
#include <math.h>

#define GN 1024
#define GM 32
#define GD 512

// ---------------- ws layout (floats) ----------------
// S      : GN*GD            = 524288
// invSn  : GN               = 1024
// invxn  : GN*GM            = 32768
// csown  : GN*GM            = 32768  (already w*clamp(cos)+b)
// pm     : GN*GM*16         = 524288
// ps     : GN*GM*16         = 524288
#define WS_S      0
#define WS_INVSN  (WS_S + GN*GD)
#define WS_INVXN  (WS_INVSN + GN)
#define WS_CSOWN  (WS_INVXN + GN*GM)
#define WS_PM     (WS_CSOWN + GN*GM)
#define WS_PS     (WS_PM + GN*GM*16)

// ---------------------------------------------------------------------------
// Kernel A: per speaker n — centroid sums, norms, own-centroid cosine.
// grid GN blocks, 512 threads.
// ---------------------------------------------------------------------------
__global__ __launch_bounds__(512) void prep_kernel(
    const float* __restrict__ x, const float* __restrict__ wp,
    const float* __restrict__ bp, float* __restrict__ ws)
{
    float* S     = ws + WS_S;
    float* invSn = ws + WS_INVSN;
    float* invxn = ws + WS_INVXN;
    float* csown = ws + WS_CSOWN;

    const int n = blockIdx.x;
    const int d = threadIdx.x;           // 0..511
    const int lane = threadIdx.x & 63;
    const int wid  = threadIdx.x >> 6;   // 0..7

    __shared__ float sS[GD];
    __shared__ float red[8];
    __shared__ float sSn2;

    const float* xn_ = x + (size_t)n * GM * GD;

    // phase 1: column sums S[n,d]
    float Sd = 0.f;
    #pragma unroll
    for (int m = 0; m < GM; ++m) Sd += xn_[m * GD + d];
    sS[d] = Sd;
    S[(size_t)n * GD + d] = Sd;

    // block reduce Sd^2 -> ||S||^2
    float p = Sd * Sd;
    #pragma unroll
    for (int off = 32; off > 0; off >>= 1) p += __shfl_down(p, off);
    if (lane == 0) red[wid] = p;
    __syncthreads();
    if (threadIdx.x == 0) {
        float s = 0.f;
        #pragma unroll
        for (int i = 0; i < 8; ++i) s += red[i];
        sSn2 = s;
        invSn[n] = rsqrtf(s);
    }
    __syncthreads();

    // phase 2: per-utterance norms + dot(x, S); wave wid handles m = wid + 8*mm
    const float w0 = wp[0], b0 = bp[0];
    const float Sn2 = sSn2;
    #pragma unroll
    for (int mm = 0; mm < 4; ++mm) {
        const int m = wid + mm * 8;
        float xn2 = 0.f, dn = 0.f;
        #pragma unroll
        for (int j = 0; j < 8; ++j) {
            float xv = xn_[m * GD + lane + 64 * j];
            float sv = sS[lane + 64 * j];
            xn2 += xv * xv;
            dn  += xv * sv;
        }
        #pragma unroll
        for (int off = 32; off > 0; off >>= 1) {
            xn2 += __shfl_down(xn2, off);
            dn  += __shfl_down(dn, off);
        }
        if (lane == 0) {
            float ixn = rsqrtf(xn2);
            float en2 = Sn2 - 2.f * dn + xn2;          // ||S - x||^2
            float cosown = (dn - xn2) * ixn * rsqrtf(en2);
            csown[n * GM + m] = w0 * fmaxf(cosown, 1e-6f) + b0;
            invxn[n * GM + m] = ixn;
        }
    }
}

// ---------------------------------------------------------------------------
// Kernel B: GEMM G = x_flat(32768 x 512) * S^T(512 x 1024), fused epilogue:
// scaled-cosine logits + per-row partial softmax (max, sumexp) over the
// 64-col tile. grid (16 colblocks, 512 rowblocks), 256 threads, 64x64 tile.
// ---------------------------------------------------------------------------
__global__ __launch_bounds__(256) void gemm_kernel(
    const float* __restrict__ x, const float* __restrict__ wp,
    const float* __restrict__ bp, float* __restrict__ ws)
{
    const float* S     = ws + WS_S;
    const float* invSn = ws + WS_INVSN;
    const float* invxn = ws + WS_INVXN;
    const float* csown = ws + WS_CSOWN;
    float* pm          = ws + WS_PM;
    float* ps          = ws + WS_PS;

    __shared__ float As[32][68];
    __shared__ float Bs[32][68];

    const int t  = threadIdx.x;
    const int ty = t >> 4;       // 0..15
    const int tx = t & 15;       // 0..15
    const int rbase = blockIdx.y * 64;
    const int cbase = blockIdx.x * 64;

    const int lc = t & 7;        // k-quad within 32-k step
    const int lr = t >> 3;       // 0..31

    float acc[4][4];
    #pragma unroll
    for (int i = 0; i < 4; ++i)
        #pragma unroll
        for (int j = 0; j < 4; ++j) acc[i][j] = 0.f;

    for (int k0 = 0; k0 < GD; k0 += 32) {
        #pragma unroll
        for (int pth = 0; pth < 2; ++pth) {
            const int r = lr + pth * 32;
            float4 av = *(const float4*)&x[(size_t)(rbase + r) * GD + k0 + lc * 4];
            float4 bv = *(const float4*)&S[(size_t)(cbase + r) * GD + k0 + lc * 4];
            As[lc * 4 + 0][r] = av.x; As[lc * 4 + 1][r] = av.y;
            As[lc * 4 + 2][r] = av.z; As[lc * 4 + 3][r] = av.w;
            Bs[lc * 4 + 0][r] = bv.x; Bs[lc * 4 + 1][r] = bv.y;
            Bs[lc * 4 + 2][r] = bv.z; Bs[lc * 4 + 3][r] = bv.w;
        }
        __syncthreads();
        #pragma unroll
        for (int k = 0; k < 32; ++k) {
            float4 a = *(const float4*)&As[k][ty * 4];
            float4 b = *(const float4*)&Bs[k][tx * 4];
            float aa[4] = {a.x, a.y, a.z, a.w};
            float bb[4] = {b.x, b.y, b.z, b.w};
            #pragma unroll
            for (int i = 0; i < 4; ++i)
                #pragma unroll
                for (int j = 0; j < 4; ++j) acc[i][j] = fmaf(aa[i], bb[j], acc[i][j]);
        }
        __syncthreads();
    }

    // epilogue: logits + partial softmax over this 64-col tile
    const float w0 = wp[0], b0 = bp[0];
    float ixn[4], isn[4];
    #pragma unroll
    for (int i = 0; i < 4; ++i) ixn[i] = invxn[rbase + ty * 4 + i];
    #pragma unroll
    for (int j = 0; j < 4; ++j) isn[j] = invSn[cbase + tx * 4 + j];

    #pragma unroll
    for (int i = 0; i < 4; ++i) {
        const int row = rbase + ty * 4 + i;
        const int own = row >> 5;       // speaker index of this row
        float v[4];
        #pragma unroll
        for (int j = 0; j < 4; ++j) {
            const int col = cbase + tx * 4 + j;
            float cs = w0 * fmaxf(acc[i][j] * ixn[i] * isn[j], 1e-6f) + b0;
            if (col == own) cs = csown[row];
            v[j] = cs;
        }
        float mx = fmaxf(fmaxf(v[0], v[1]), fmaxf(v[2], v[3]));
        #pragma unroll
        for (int off = 1; off < 16; off <<= 1) mx = fmaxf(mx, __shfl_xor(mx, off, 16));
        float se = expf(v[0] - mx) + expf(v[1] - mx) + expf(v[2] - mx) + expf(v[3] - mx);
        #pragma unroll
        for (int off = 1; off < 16; off <<= 1) se += __shfl_xor(se, off, 16);
        if (tx == 0) {
            pm[(size_t)row * 16 + blockIdx.x] = mx;
            ps[(size_t)row * 16 + blockIdx.x] = se;
        }
    }
}

// ---------------------------------------------------------------------------
// Kernel C: combine 16 softmax partials per row, loss = lse - cs_diag,
// mean-reduce into d_out[0]. 32768 rows / 256 threads = 128 blocks.
// ---------------------------------------------------------------------------
__global__ __launch_bounds__(256) void finalize_kernel(
    const float* __restrict__ ws_c, float* __restrict__ out)
{
    const float* csown = ws_c + WS_CSOWN;
    const float* pm    = ws_c + WS_PM;
    const float* ps    = ws_c + WS_PS;

    const int row = blockIdx.x * 256 + threadIdx.x;
    float mv[16];
    float m = -3.4e38f;
    #pragma unroll
    for (int i = 0; i < 16; ++i) {
        mv[i] = pm[(size_t)row * 16 + i];
        m = fmaxf(m, mv[i]);
    }
    float s = 0.f;
    #pragma unroll
    for (int i = 0; i < 16; ++i) s += ps[(size_t)row * 16 + i] * expf(mv[i] - m);
    float loss = m + logf(s) - csown[row];

    // block reduce
    const int lane = threadIdx.x & 63;
    const int wid  = threadIdx.x >> 6;
    __shared__ float red[4];
    #pragma unroll
    for (int off = 32; off > 0; off >>= 1) loss += __shfl_down(loss, off);
    if (lane == 0) red[wid] = loss;
    __syncthreads();
    if (threadIdx.x == 0) {
        float sum = red[0] + red[1] + red[2] + red[3];
        atomicAdd(out, sum * (1.f / (GN * GM)));
    }
}

extern "C" void kernel_launch(void* const* d_in, const int* in_sizes, int n_in,
                              void* d_out, int out_size, void* d_ws, size_t ws_size,
                              hipStream_t stream)
{
    const float* x  = (const float*)d_in[0];
    const float* wp = (const float*)d_in[1];
    const float* bp = (const float*)d_in[2];
    float* out = (float*)d_out;
    float* ws  = (float*)d_ws;

    hipMemsetAsync(d_out, 0, sizeof(float), stream);

    prep_kernel<<<GN, 512, 0, stream>>>(x, wp, bp, ws);

    dim3 ggrid(16, 512);
    gemm_kernel<<<ggrid, 256, 0, stream>>>(x, wp, bp, ws);

    finalize_kernel<<<128, 256, 0, stream>>>(ws, out);
}

// Round 2
// 132.996 us; speedup vs baseline: 3.7617x; 3.7617x over previous
//
#include <hip/hip_runtime.h>
#include <hip/hip_bf16.h>
#include <math.h>

#define GN 1024
#define GM 32
#define GD 512
#define NROW (GN*GM)   // 32768

// ---------------- ws layout (bytes) ----------------
#define WS_XB    0ull                  // bf16 [NROW][GD]  = 33554432 B
#define WS_SB    33554432ull           // bf16 [GN][GD]    =  1048576 B
#define WS_INVSN 34603008ull           // f32  [GN]        =     4096 B
#define WS_INVXN 34607104ull           // f32  [NROW]      =   131072 B
#define WS_CSOWN 34738176ull           // f32  [NROW]      =   131072 B
#define WS_PM    34869248ull           // f32  [NROW*16]   =  2097152 B
#define WS_PS    36966400ull           // f32  [NROW*16]   =  2097152 B

typedef __attribute__((ext_vector_type(8))) short bf16x8;
typedef __attribute__((ext_vector_type(4))) float f32x4;

// ---------------------------------------------------------------------------
// Kernel A: per speaker n — centroid sums, norms, own-centroid cosine,
// plus bf16 conversion of x and S for the MFMA GEMM.
// grid GN blocks, 512 threads.
// ---------------------------------------------------------------------------
__global__ __launch_bounds__(512) void prep_kernel(
    const float* __restrict__ x, const float* __restrict__ wp,
    const float* __restrict__ bp, char* __restrict__ wsb)
{
    __hip_bfloat16* xbw  = (__hip_bfloat16*)(wsb + WS_XB);
    __hip_bfloat16* Sbw  = (__hip_bfloat16*)(wsb + WS_SB);
    float* invSn = (float*)(wsb + WS_INVSN);
    float* invxn = (float*)(wsb + WS_INVXN);
    float* csown = (float*)(wsb + WS_CSOWN);

    const int n = blockIdx.x;
    const int d = threadIdx.x;           // 0..511
    const int lane = threadIdx.x & 63;
    const int wid  = threadIdx.x >> 6;   // 0..7

    __shared__ float sS[GD];
    __shared__ float red[8];
    __shared__ float sSn2;

    const float* xn_ = x + (size_t)n * GM * GD;

    // phase 1: column sums S[n,d] + bf16 conversion of x
    float Sd = 0.f;
    #pragma unroll
    for (int m = 0; m < GM; ++m) {
        float xv = xn_[m * GD + d];
        Sd += xv;
        xbw[(size_t)(n * GM + m) * GD + d] = __float2bfloat16(xv);
    }
    sS[d] = Sd;
    Sbw[(size_t)n * GD + d] = __float2bfloat16(Sd);

    // block reduce Sd^2 -> ||S||^2
    float p = Sd * Sd;
    #pragma unroll
    for (int off = 32; off > 0; off >>= 1) p += __shfl_down(p, off);
    if (lane == 0) red[wid] = p;
    __syncthreads();
    if (threadIdx.x == 0) {
        float s = 0.f;
        #pragma unroll
        for (int i = 0; i < 8; ++i) s += red[i];
        sSn2 = s;
        invSn[n] = rsqrtf(s);
    }
    __syncthreads();

    // phase 2: per-utterance norms + dot(x, S)
    const float w0 = wp[0], b0 = bp[0];
    const float Sn2 = sSn2;
    #pragma unroll
    for (int mm = 0; mm < 4; ++mm) {
        const int m = wid + mm * 8;
        float xn2 = 0.f, dn = 0.f;
        #pragma unroll
        for (int j = 0; j < 8; ++j) {
            float xv = xn_[m * GD + lane + 64 * j];
            float sv = sS[lane + 64 * j];
            xn2 += xv * xv;
            dn  += xv * sv;
        }
        #pragma unroll
        for (int off = 32; off > 0; off >>= 1) {
            xn2 += __shfl_down(xn2, off);
            dn  += __shfl_down(dn, off);
        }
        if (lane == 0) {
            float ixn = rsqrtf(xn2);
            float en2 = Sn2 - 2.f * dn + xn2;          // ||S - x||^2
            float cosown = (dn - xn2) * ixn * rsqrtf(en2);
            csown[n * GM + m] = w0 * fmaxf(cosown, 1e-6f) + b0;
            invxn[n * GM + m] = ixn;
        }
    }
}

// ---------------------------------------------------------------------------
// Kernel B: bf16 MFMA GEMM G = xb(32768x512) * Sb^T(512x1024), m97-style
// 128x128 tile / BK=32 / 4 waves (2x2) / 4x4 16x16x32 fragments per wave.
// Fused epilogue: scaled-cosine logits + per-wave-col (64-wide) partial
// softmax. grid (8 colblocks, 256 rowblocks), 256 threads.
// LDS layout [kb][row][8] so fragment reads are single ds_read_b128.
// ---------------------------------------------------------------------------
__global__ __launch_bounds__(256) void gemm_kernel(
    const float* __restrict__ wp, const float* __restrict__ bp,
    char* __restrict__ wsb)
{
    const __hip_bfloat16* xb  = (const __hip_bfloat16*)(wsb + WS_XB);
    const __hip_bfloat16* Sbm = (const __hip_bfloat16*)(wsb + WS_SB);
    const float* invSn = (const float*)(wsb + WS_INVSN);
    const float* invxn = (const float*)(wsb + WS_INVXN);
    const float* csown = (const float*)(wsb + WS_CSOWN);
    float* pm = (float*)(wsb + WS_PM);
    float* ps = (float*)(wsb + WS_PS);

    __shared__ __hip_bfloat16 Ab[512][8];   // slot s = kb*128+row, 16B each
    __shared__ __hip_bfloat16 Bb[512][8];

    const int t    = threadIdx.x;
    const int w    = t >> 6;
    const int lane = t & 63;
    const int wr   = w >> 1, wc = w & 1;
    const int rbase = blockIdx.y * 128;
    const int cbase = blockIdx.x * 128;

    const int kb  = lane >> 4;   // k-group 0..3 (also C row-group)
    const int r16 = lane & 15;

    f32x4 acc[4][4] = {};

    for (int ks = 0; ks < 16; ++ks) {
        const int k0 = ks * 32;
        #pragma unroll
        for (int p = 0; p < 2; ++p) {
            const int s    = (w * 2 + p) * 64 + lane;   // slot this lane fills
            const int skb  = s >> 7;
            const int srow = s & 127;
            const __hip_bfloat16* ga = xb  + (size_t)(rbase + srow) * GD + (k0 + skb * 8);
            const __hip_bfloat16* gb = Sbm + (size_t)(cbase + srow) * GD + (k0 + skb * 8);
            __builtin_amdgcn_global_load_lds(
                (const __attribute__((address_space(1))) void*)ga,
                (__attribute__((address_space(3))) void*)&Ab[(w * 2 + p) * 64][0],
                16, 0, 0);
            __builtin_amdgcn_global_load_lds(
                (const __attribute__((address_space(1))) void*)gb,
                (__attribute__((address_space(3))) void*)&Bb[(w * 2 + p) * 64][0],
                16, 0, 0);
        }
        __syncthreads();

        bf16x8 af[4], bfr[4];
        #pragma unroll
        for (int mi = 0; mi < 4; ++mi)
            af[mi] = *(const bf16x8*)&Ab[kb * 128 + wr * 64 + mi * 16 + r16][0];
        #pragma unroll
        for (int nj = 0; nj < 4; ++nj)
            bfr[nj] = *(const bf16x8*)&Bb[kb * 128 + wc * 64 + nj * 16 + r16][0];
        #pragma unroll
        for (int mi = 0; mi < 4; ++mi)
            #pragma unroll
            for (int nj = 0; nj < 4; ++nj)
                acc[mi][nj] = __builtin_amdgcn_mfma_f32_16x16x32_bf16(
                    af[mi], bfr[nj], acc[mi][nj], 0, 0, 0);
        __syncthreads();
    }

    // ---- fused epilogue: logits + per-wave 64-col softmax partials ----
    const float w0 = wp[0], b0 = bp[0];
    const int pcol = blockIdx.x * 2 + wc;      // 0..15 partial slot
    float isn[4];
    #pragma unroll
    for (int nj = 0; nj < 4; ++nj)
        isn[nj] = invSn[cbase + wc * 64 + nj * 16 + r16];

    #pragma unroll
    for (int mi = 0; mi < 4; ++mi) {
        #pragma unroll
        for (int r = 0; r < 4; ++r) {
            const int row = rbase + wr * 64 + mi * 16 + kb * 4 + r;
            const float ixn = invxn[row];
            const float cso = csown[row];
            const int own = row >> 5;
            float v[4];
            #pragma unroll
            for (int nj = 0; nj < 4; ++nj) {
                const int col = cbase + wc * 64 + nj * 16 + r16;
                float cs = w0 * fmaxf(acc[mi][nj][r] * ixn * isn[nj], 1e-6f) + b0;
                v[nj] = (col == own) ? cso : cs;
            }
            float mx = fmaxf(fmaxf(v[0], v[1]), fmaxf(v[2], v[3]));
            #pragma unroll
            for (int off = 1; off < 16; off <<= 1)
                mx = fmaxf(mx, __shfl_xor(mx, off, 16));
            float se = __expf(v[0] - mx) + __expf(v[1] - mx)
                     + __expf(v[2] - mx) + __expf(v[3] - mx);
            #pragma unroll
            for (int off = 1; off < 16; off <<= 1)
                se += __shfl_xor(se, off, 16);
            if (r16 == 0) {
                pm[(size_t)row * 16 + pcol] = mx;
                ps[(size_t)row * 16 + pcol] = se;
            }
        }
    }
}

// ---------------------------------------------------------------------------
// Kernel C: combine 16 softmax partials per row, loss = lse - cs_own,
// mean-reduce into d_out[0]. 32768 rows / 256 threads = 128 blocks.
// ---------------------------------------------------------------------------
__global__ __launch_bounds__(256) void finalize_kernel(
    const char* __restrict__ wsb, float* __restrict__ out)
{
    const float* csown = (const float*)(wsb + WS_CSOWN);
    const float* pm    = (const float*)(wsb + WS_PM);
    const float* ps    = (const float*)(wsb + WS_PS);

    const int row = blockIdx.x * 256 + threadIdx.x;
    float mv[16];
    float m = -3.4e38f;
    #pragma unroll
    for (int i = 0; i < 16; ++i) {
        mv[i] = pm[(size_t)row * 16 + i];
        m = fmaxf(m, mv[i]);
    }
    float s = 0.f;
    #pragma unroll
    for (int i = 0; i < 16; ++i) s += ps[(size_t)row * 16 + i] * expf(mv[i] - m);
    float loss = m + logf(s) - csown[row];

    const int lane = threadIdx.x & 63;
    const int wid  = threadIdx.x >> 6;
    __shared__ float red[4];
    #pragma unroll
    for (int off = 32; off > 0; off >>= 1) loss += __shfl_down(loss, off);
    if (lane == 0) red[wid] = loss;
    __syncthreads();
    if (threadIdx.x == 0) {
        float sum = red[0] + red[1] + red[2] + red[3];
        atomicAdd(out, sum * (1.f / (GN * GM)));
    }
}

extern "C" void kernel_launch(void* const* d_in, const int* in_sizes, int n_in,
                              void* d_out, int out_size, void* d_ws, size_t ws_size,
                              hipStream_t stream)
{
    const float* x  = (const float*)d_in[0];
    const float* wp = (const float*)d_in[1];
    const float* bp = (const float*)d_in[2];
    float* out = (float*)d_out;
    char* wsb  = (char*)d_ws;

    hipMemsetAsync(d_out, 0, sizeof(float), stream);

    prep_kernel<<<GN, 512, 0, stream>>>(x, wp, bp, wsb);

    dim3 ggrid(8, 256);
    gemm_kernel<<<ggrid, 256, 0, stream>>>(wp, bp, wsb);

    finalize_kernel<<<128, 256, 0, stream>>>(wsb, out);
}

// Round 3
// 118.542 us; speedup vs baseline: 4.2204x; 1.1219x over previous
//
#include <hip/hip_runtime.h>
#include <hip/hip_bf16.h>
#include <math.h>

#define GN 1024
#define GM 32
#define GD 512
#define NROW (GN*GM)   // 32768

// ---------------- ws layout (bytes) ----------------
#define WS_XB    0ull                  // bf16 [NROW][GD]  = 33554432 B
#define WS_SB    33554432ull           // bf16 [GN][GD]    =  1048576 B
#define WS_INVSN 34603008ull           // f32  [GN]        =     4096 B
#define WS_INVXN 34607104ull           // f32  [NROW]      =   131072 B
#define WS_CSOWN 34738176ull           // f32  [NROW]      =   131072 B
#define WS_PS    34869248ull           // f32  [NROW*16]   =  2097152 B

typedef __attribute__((ext_vector_type(8))) short bf16x8;
typedef __attribute__((ext_vector_type(4))) float f32x4;

// ---------------------------------------------------------------------------
// Kernel A: per speaker n — centroid sums, norms, own-centroid cosine,
// plus bf16 conversion of x and S for the MFMA GEMM.
// grid GN blocks, 512 threads.
// ---------------------------------------------------------------------------
__global__ __launch_bounds__(512) void prep_kernel(
    const float* __restrict__ x, const float* __restrict__ wp,
    const float* __restrict__ bp, char* __restrict__ wsb)
{
    __hip_bfloat16* xbw  = (__hip_bfloat16*)(wsb + WS_XB);
    __hip_bfloat16* Sbw  = (__hip_bfloat16*)(wsb + WS_SB);
    float* invSn = (float*)(wsb + WS_INVSN);
    float* invxn = (float*)(wsb + WS_INVXN);
    float* csown = (float*)(wsb + WS_CSOWN);

    const int n = blockIdx.x;
    const int d = threadIdx.x;           // 0..511
    const int lane = threadIdx.x & 63;
    const int wid  = threadIdx.x >> 6;   // 0..7

    __shared__ float sS[GD];
    __shared__ float red[8];
    __shared__ float sSn2;

    const float* xn_ = x + (size_t)n * GM * GD;

    // phase 1: column sums S[n,d] + bf16 conversion of x
    float Sd = 0.f;
    #pragma unroll
    for (int m = 0; m < GM; ++m) {
        float xv = xn_[m * GD + d];
        Sd += xv;
        xbw[(size_t)(n * GM + m) * GD + d] = __float2bfloat16(xv);
    }
    sS[d] = Sd;
    Sbw[(size_t)n * GD + d] = __float2bfloat16(Sd);

    // block reduce Sd^2 -> ||S||^2
    float p = Sd * Sd;
    #pragma unroll
    for (int off = 32; off > 0; off >>= 1) p += __shfl_down(p, off);
    if (lane == 0) red[wid] = p;
    __syncthreads();
    if (threadIdx.x == 0) {
        float s = 0.f;
        #pragma unroll
        for (int i = 0; i < 8; ++i) s += red[i];
        sSn2 = s;
        invSn[n] = rsqrtf(s);
    }
    __syncthreads();

    // phase 2: per-utterance norms + dot(x, S)
    const float w0 = wp[0], b0 = bp[0];
    const float Sn2 = sSn2;
    #pragma unroll
    for (int mm = 0; mm < 4; ++mm) {
        const int m = wid + mm * 8;
        float xn2 = 0.f, dn = 0.f;
        #pragma unroll
        for (int j = 0; j < 8; ++j) {
            float xv = xn_[m * GD + lane + 64 * j];
            float sv = sS[lane + 64 * j];
            xn2 += xv * xv;
            dn  += xv * sv;
        }
        #pragma unroll
        for (int off = 32; off > 0; off >>= 1) {
            xn2 += __shfl_down(xn2, off);
            dn  += __shfl_down(dn, off);
        }
        if (lane == 0) {
            float ixn = rsqrtf(xn2);
            float en2 = Sn2 - 2.f * dn + xn2;          // ||S - x||^2
            float cosown = (dn - xn2) * ixn * rsqrtf(en2);
            csown[n * GM + m] = w0 * fmaxf(cosown, 1e-6f) + b0;
            invxn[n * GM + m] = ixn;
        }
    }
}

// ---------------------------------------------------------------------------
// Kernel B: bf16 MFMA GEMM G = xb(32768x512) * Sb^T(512x1024).
// 128x128 tile / BK=32 / 4 waves (2x2) / 4x4 16x16x32 fragments per wave.
// Double-buffered LDS, next-tile global_load_lds issued BEFORE current-tile
// compute (T3 minimum-2-phase). Fused epilogue: fixed-shift partial softmax
// (logits bounded by C = max(w+b, w*1e-6+b)); only sum partials written.
// grid (256 rowblocks, 8 colblocks), 256 threads.
// ---------------------------------------------------------------------------
__global__ __launch_bounds__(256) void gemm_kernel(
    const float* __restrict__ wp, const float* __restrict__ bp,
    char* __restrict__ wsb)
{
    const __hip_bfloat16* xb  = (const __hip_bfloat16*)(wsb + WS_XB);
    const __hip_bfloat16* Sbm = (const __hip_bfloat16*)(wsb + WS_SB);
    const float* invSn = (const float*)(wsb + WS_INVSN);
    const float* invxn = (const float*)(wsb + WS_INVXN);
    const float* csown = (const float*)(wsb + WS_CSOWN);
    float* ps = (float*)(wsb + WS_PS);

    // slot s = kb*128 + row; each slot = 8 bf16 = 16 B (one fragment k-chunk)
    __shared__ __align__(16) __hip_bfloat16 Ab[2][512][8];
    __shared__ __align__(16) __hip_bfloat16 Bb[2][512][8];

    const int t    = threadIdx.x;
    const int w    = t >> 6;
    const int lane = t & 63;
    const int wr   = w >> 1, wc = w & 1;
    const int rbase = blockIdx.x * 128;
    const int cbase = blockIdx.y * 128;

    const int kb  = lane >> 4;   // k-group 0..3 (also C row-group)
    const int r16 = lane & 15;

    f32x4 acc[4][4] = {};

    // staging slots for this thread: s = p*256 + t, p = 0..1
    const int s0 = t, s1 = 256 + t;
    const int arow0 = rbase + (s0 & 127), akb0 = (s0 >> 7) * 8;
    const int arow1 = rbase + (s1 & 127), akb1 = (s1 >> 7) * 8;
    const int brow0 = cbase + (s0 & 127);
    const int brow1 = cbase + (s1 & 127);
    // wave-uniform LDS bases (HW adds lane*16)
    const int base0 = (t >> 6) * 64;          // slot base for p=0
    const int base1 = 256 + (t >> 6) * 64;    // slot base for p=1

#define STAGE(buf, k0)                                                         \
    do {                                                                       \
        __builtin_amdgcn_global_load_lds(                                      \
            (const __attribute__((address_space(1))) void*)(xb +               \
                (size_t)arow0 * GD + (k0) + akb0),                             \
            (__attribute__((address_space(3))) void*)&Ab[buf][base0][0],       \
            16, 0, 0);                                                         \
        __builtin_amdgcn_global_load_lds(                                      \
            (const __attribute__((address_space(1))) void*)(xb +               \
                (size_t)arow1 * GD + (k0) + akb1),                             \
            (__attribute__((address_space(3))) void*)&Ab[buf][base1][0],       \
            16, 0, 0);                                                         \
        __builtin_amdgcn_global_load_lds(                                      \
            (const __attribute__((address_space(1))) void*)(Sbm +              \
                (size_t)brow0 * GD + (k0) + akb0),                             \
            (__attribute__((address_space(3))) void*)&Bb[buf][base0][0],       \
            16, 0, 0);                                                         \
        __builtin_amdgcn_global_load_lds(                                      \
            (const __attribute__((address_space(1))) void*)(Sbm +              \
                (size_t)brow1 * GD + (k0) + akb1),                             \
            (__attribute__((address_space(3))) void*)&Bb[buf][base1][0],       \
            16, 0, 0);                                                         \
    } while (0)

    STAGE(0, 0);
    __syncthreads();            // vmcnt(0) drain + barrier: buf0 ready

    int cur = 0;
    for (int ks = 0; ks < 16; ++ks) {
        if (ks < 15) STAGE(cur ^ 1, (ks + 1) * 32);   // prefetch next tile

        bf16x8 af[4], bfr[4];
        #pragma unroll
        for (int mi = 0; mi < 4; ++mi)
            af[mi] = *(const bf16x8*)&Ab[cur][kb * 128 + wr * 64 + mi * 16 + r16][0];
        #pragma unroll
        for (int nj = 0; nj < 4; ++nj)
            bfr[nj] = *(const bf16x8*)&Bb[cur][kb * 128 + wc * 64 + nj * 16 + r16][0];
        #pragma unroll
        for (int mi = 0; mi < 4; ++mi)
            #pragma unroll
            for (int nj = 0; nj < 4; ++nj)
                acc[mi][nj] = __builtin_amdgcn_mfma_f32_16x16x32_bf16(
                    af[mi], bfr[nj], acc[mi][nj], 0, 0, 0);

        __syncthreads();        // drains this wave's prefetch too
        cur ^= 1;
    }
#undef STAGE

    // ---- fused epilogue: fixed-shift partial softmax over 64-col wave tile
    const float w0 = wp[0], b0 = bp[0];
    const float C = fmaxf(w0 * 1e-6f + b0, w0 + b0);   // logit upper bound
    const int pcol = blockIdx.y * 2 + wc;              // 0..15 partial slot
    float isn[4];
    #pragma unroll
    for (int nj = 0; nj < 4; ++nj)
        isn[nj] = invSn[cbase + wc * 64 + nj * 16 + r16];

    #pragma unroll
    for (int mi = 0; mi < 4; ++mi) {
        #pragma unroll
        for (int r = 0; r < 4; ++r) {
            const int row = rbase + wr * 64 + mi * 16 + kb * 4 + r;
            const float ixn = invxn[row];
            const float cso = csown[row];
            const int own = row >> 5;
            float se = 0.f;
            #pragma unroll
            for (int nj = 0; nj < 4; ++nj) {
                const int col = cbase + wc * 64 + nj * 16 + r16;
                float cs = w0 * fmaxf(acc[mi][nj][r] * ixn * isn[nj], 1e-6f) + b0;
                cs = (col == own) ? cso : cs;
                se += __expf(cs - C);
            }
            #pragma unroll
            for (int off = 1; off < 16; off <<= 1)
                se += __shfl_xor(se, off, 16);
            if (r16 == 0)
                ps[(size_t)row * 16 + pcol] = se;
        }
    }
}

// ---------------------------------------------------------------------------
// Kernel C: combine 16 sum-partials per row (shared fixed shift C),
// loss = C + log(sum) - cs_own, mean-reduce into d_out[0].
// ---------------------------------------------------------------------------
__global__ __launch_bounds__(256) void finalize_kernel(
    const char* __restrict__ wsb, const float* __restrict__ wp,
    const float* __restrict__ bp, float* __restrict__ out)
{
    const float* csown = (const float*)(wsb + WS_CSOWN);
    const float* ps    = (const float*)(wsb + WS_PS);

    const float w0 = wp[0], b0 = bp[0];
    const float C = fmaxf(w0 * 1e-6f + b0, w0 + b0);

    const int row = blockIdx.x * 256 + threadIdx.x;
    float s = 0.f;
    #pragma unroll
    for (int i = 0; i < 16; ++i) s += ps[(size_t)row * 16 + i];
    float loss = C + logf(s) - csown[row];

    const int lane = threadIdx.x & 63;
    const int wid  = threadIdx.x >> 6;
    __shared__ float red[4];
    #pragma unroll
    for (int off = 32; off > 0; off >>= 1) loss += __shfl_down(loss, off);
    if (lane == 0) red[wid] = loss;
    __syncthreads();
    if (threadIdx.x == 0) {
        float sum = red[0] + red[1] + red[2] + red[3];
        atomicAdd(out, sum * (1.f / (GN * GM)));
    }
}

extern "C" void kernel_launch(void* const* d_in, const int* in_sizes, int n_in,
                              void* d_out, int out_size, void* d_ws, size_t ws_size,
                              hipStream_t stream)
{
    const float* x  = (const float*)d_in[0];
    const float* wp = (const float*)d_in[1];
    const float* bp = (const float*)d_in[2];
    float* out = (float*)d_out;
    char* wsb  = (char*)d_ws;

    hipMemsetAsync(d_out, 0, sizeof(float), stream);

    prep_kernel<<<GN, 512, 0, stream>>>(x, wp, bp, wsb);

    dim3 ggrid(256, 8);
    gemm_kernel<<<ggrid, 256, 0, stream>>>(wp, bp, wsb);

    finalize_kernel<<<128, 256, 0, stream>>>(wsb, wp, bp, out);
}